// Round 11
// baseline (93.146 us; speedup 1.0000x reference)
//
#include <hip/hip_runtime.h>

#define TLEN 512
#define LOG2E 1.44269504088896340736f

#if __has_builtin(__builtin_amdgcn_exp2f)
#define EXP2F(x) __builtin_amdgcn_exp2f(x)
#else
#define EXP2F(x) __exp2f(x)
#endif
#if __has_builtin(__builtin_amdgcn_rcpf)
#define RCPF(x) __builtin_amdgcn_rcpf(x)
#else
#define RCPF(x) (1.0f / (x))
#endif

// ds_swizzle BitMode xor (epilogue MLP head only, off the hot loop)
#define SWZ(v, xm) __int_as_float(__builtin_amdgcn_ds_swizzle(__float_as_int(v), (((xm) << 10) | 0x1F)))
// Generic DPP: dst = src[permuted lane], all lanes valid
#define DPPF(v, ctrl) __int_as_float(__builtin_amdgcn_update_dpp(__float_as_int(v), __float_as_int(v), (ctrl), 0xF, 0xF, false))
// quad_perm broadcast of quad-lane k
#define QB(v, k) DPPF(v, 0x55 * (k))
// Direction-free lane exchanges within a row of 16 (verified R1-R10, absmax 0):
#define XOR3(v)  DPPF(v, 0x1B)   // quad_perm [3,2,1,0]
#define XOR7(v)  DPPF(v, 0x141)  // ROW_HALF_MIRROR
#define XOR8(v)  DPPF(v, 0x128)  // ROW_ROR:8

// counted vmcnt wait + full scheduling fence (rule #18); keeps the vmcnt
// arithmetic exact (nothing migrates across iteration boundaries).
#define WAITVM(N) { \
    asm volatile("s_waitcnt vmcnt(" #N ")" ::: "memory"); \
    __builtin_amdgcn_sched_barrier(0); }

typedef const __attribute__((address_space(1))) unsigned int gu32;
typedef __attribute__((address_space(3))) unsigned int lu32;

// R11: R10's proven global_load_lds DMA ring (fire-and-forget, no register
// for RA to corrupt; absmax 0 twice) with two repairs:
//  1) ring 4 -> 8 slots: prefetch distance 7 groups >> HBM latency.
//  2) per-step interleave FORCED at source: each step = [issue 4 ds_read of
//     next group's step] sched_barrier(0) [STEP chain || dot FMAs]. R10's
//     monolithic REFILL-then-4xSTEP let the scheduler serialize ds-latency
//     and chain-latency back to back (1500cy stall/group).
__global__ __launch_bounds__(256)
__attribute__((amdgpu_waves_per_eu(1, 1)))
void lstm_mlp_kernel(
    const float* __restrict__ x,   // [B,512,16]
    const float* __restrict__ Wk,  // [16,16]
    const float* __restrict__ Wr,  // [4,16]
    const float* __restrict__ bg,  // [16]
    const float* __restrict__ W1,  // [4,64]
    const float* __restrict__ b1,  // [64]
    const float* __restrict__ W2,  // [64,5]
    const float* __restrict__ b2,  // [5]
    float* __restrict__ out,       // [B,5]
    int B)
{
    // per-wave private LDS ring: [wave][slot][dt*16 + chunk*4 + seq] float4
    // slot = one group of 4 timesteps (1KB); 8 slots x 4 waves = 32KB.
    // Wave-private -> no barriers anywhere.
    __shared__ float4 lds[4][8][64];

    const int tidx = threadIdx.x;
    const int w   = tidx >> 6;         // wave in block
    const int L   = tidx & 63;         // lane
    const int sl  = (tidx >> 4) & 3;   // seq-local within wave
    const int i16 = tidx & 15;
    const int j   = i16 >> 2;          // hidden unit owned by this quad
    const int q   = i16 & 3;           // gate type: 0=i, 1=f, 2=g(tanh), 3=o
    const int gate = q * 4 + j;        // column in gates[16] (Keras i,f,g,o)
    const int seq = blockIdx.x * 16 + (tidx >> 4);

    // activation pre-scale folded into weights (verified R2/R6-R10, absmax 0)
    const bool is_g = (q == 2);
    const float k1 = is_g ? (-2.0f * LOG2E) : (-LOG2E);
    const float m1c = is_g ? (-4.0f * LOG2E) : 1.0f;
    const float m0c = is_g ? (2.0f * LOG2E) : 0.0f;

    float wk[16];
#pragma unroll
    for (int f = 0; f < 16; ++f) wk[f] = k1 * Wk[f * 16 + gate];
    const float wr0 = k1 * Wr[(j ^ 0) * 16 + gate];
    const float wr1 = k1 * Wr[(j ^ 1) * 16 + gate];
    const float wr2 = k1 * Wr[(j ^ 2) * 16 + gate];
    const float wr3 = k1 * Wr[(j ^ 3) * 16 + gate];
    const float biasS = k1 * bg[gate];

    // DMA lane mapping (R6/R10-proven): lane L fetches the 16B of
    // (seq L&3, timestep t0+(L>>4), chunk (L>>2)&3); linear LDS dest
    // base + L*16 gives layout [dt][chunk][seq] float4.
    const int dseq = L & 3;
    const int dtl  = L >> 4;
    const int chnk = (L >> 2) & 3;
    const float* xb = x + ((size_t)(blockIdx.x * 16 + w * 4 + dseq) * TLEN + dtl) * 16 + chnk * 4;

#define DMA(SLOT, T0) \
    __builtin_amdgcn_global_load_lds((gu32*)(const void*)(xb + (size_t)(T0) * 16), \
                                     (lu32*)(void*)(&lds[w][SLOT][0]), 16, 0, 0)

    float cs = 0.0f, h = 0.0f;   // cs = -2*log2e * c

#define DOT4S(v, w0_, w1_, w2_, w3_, seed) \
    fmaf((v).x, (w0_), fmaf((v).y, (w1_), fmaf((v).z, (w2_), fmaf((v).w, (w3_), (seed)))))
#define DOTQ(Ra, Rb, Rc, Rd) \
    ((DOT4S((Ra), wk[0], wk[1], wk[2], wk[3], biasS) + \
      DOT4S((Rb), wk[4], wk[5], wk[6], wk[7], 0.0f)) + \
     (DOT4S((Rc), wk[8], wk[9], wk[10], wk[11], 0.0f) + \
      DOT4S((Rd), wk[12], wk[13], wk[14], wk[15], 0.0f)))

// tree-shaped preactivation sum, then the LSTM cell update (verified R8-R10)
#define STEP(XD) { \
    float h1_ = XOR7(XOR3(h));   /* h[j^1] */ \
    float h2_ = XOR8(h);         /* h[j^2] */ \
    float h3_ = XOR8(h1_);       /* h[j^3] */ \
    float preA = fmaf(h, wr0, fmaf(h1_, wr1, (XD))); \
    float preB = fmaf(h2_, wr2, h3_ * wr3); \
    float pre = preA + preB; \
    float r_ = RCPF(1.0f + EXP2F(pre)); \
    float av = fmaf(m1c, r_, m0c); \
    float iv = QB(av, 0); \
    float fv = QB(av, 1); \
    float gv = QB(av, 2); \
    float ov = QB(av, 3); \
    cs = fmaf(fv, cs, iv * gv); \
    float th_ = fmaf(2.0f, RCPF(1.0f + EXP2F(cs)), -1.0f); \
    h = ov * th_; }

// one step: issue the 4 broadcast ds_read_b128 of NEXT group's timestep K,
// pin them early with sched_barrier(0), then let the STEP chain (independent)
// and the dot FMAs (gated by compiler-inserted lgkmcnt) interleave.
#define BODYK(LG, K, X) { \
    float4 a_ = (LG)[(K) * 16 + sl]; \
    float4 b_ = (LG)[(K) * 16 + 4 + sl]; \
    float4 c_ = (LG)[(K) * 16 + 8 + sl]; \
    float4 d_ = (LG)[(K) * 16 + 12 + sl]; \
    __builtin_amdgcn_sched_barrier(0); \
    STEP(X); \
    X = DOTQ(a_, b_, c_, d_); }

    // prologue: clean vmcnt baseline, fill all 8 slots (groups 0..7)
    WAITVM(0);
    DMA(0, 0);  DMA(1, 4);  DMA(2, 8);  DMA(3, 12);
    DMA(4, 16); DMA(5, 20); DMA(6, 24); DMA(7, 28);
    WAITVM(7);                       // group 0 resident (7 outstanding)
    float X0, X1, X2, X3;
    {
        const float4* lg0 = &lds[w][0][0];
        float4 a0=lg0[sl+0],  a1=lg0[sl+4],  a2=lg0[sl+8],  a3=lg0[sl+12];
        float4 b0=lg0[sl+16], b1_=lg0[sl+20], b2_=lg0[sl+24], b3=lg0[sl+28];
        float4 c0=lg0[sl+32], c1=lg0[sl+36], c2=lg0[sl+40], c3=lg0[sl+44];
        float4 d0=lg0[sl+48], d1=lg0[sl+52], d2=lg0[sl+56], d3=lg0[sl+60];
        X0 = DOTQ(a0, a1, a2, a3);
        X1 = DOTQ(b0, b1_, b2_, b3);
        X2 = DOTQ(c0, c1, c2, c3);
        X3 = DOTQ(d0, d1, d2, d3);
    }

    // main loop: iter g chains steps 4g..4g+3 (X0..X3), pre-dots group g+1
    // per-step (slot (g+1)&7, resident via WAITVM(6): 7 outstanding at top,
    // retire group g+1), then DMAs group g+8 into slot g&7 (clamped tail
    // rewrites land in slots never read again).
#pragma clang loop unroll(disable)
    for (int g = 0; g < 127; ++g) {
        WAITVM(6);
        const float4* lg = &lds[w][(g + 1) & 7][0];
        BODYK(lg, 0, X0);
        BODYK(lg, 1, X1);
        BODYK(lg, 2, X2);
        BODYK(lg, 3, X3);
        int t0 = (g + 8) << 2;
        t0 = t0 > (TLEN - 4) ? (TLEN - 4) : t0;
        DMA(g & 7, t0);
    }
    // final group 127: pure chain
    STEP(X0); STEP(X1); STEP(X2); STEP(X3);
    WAITVM(0);   // drain trailing DMAs before epilogue

    // ---- MLP head (runs once; verified R2/R6-R10) ----
    float hA = h;
    float hB = SWZ(h, 4), hC = SWZ(h, 8), hD = SWZ(h, 12);

    float p0 = 0.f, p1 = 0.f, p2 = 0.f, p3 = 0.f, p4 = 0.f;
#pragma unroll
    for (int r = 0; r < 4; ++r) {
        const int u = i16 * 4 + r;            // hidden unit of layer 1, 4 per lane
        float acc = b1[u];
        acc = fmaf(hA, W1[(j ^ 0) * 64 + u], acc);
        acc = fmaf(hB, W1[(j ^ 1) * 64 + u], acc);
        acc = fmaf(hC, W1[(j ^ 2) * 64 + u], acc);
        acc = fmaf(hD, W1[(j ^ 3) * 64 + u], acc);
        acc = fmaxf(acc, 0.0f);
        p0 = fmaf(acc, W2[u * 5 + 0], p0);
        p1 = fmaf(acc, W2[u * 5 + 1], p1);
        p2 = fmaf(acc, W2[u * 5 + 2], p2);
        p3 = fmaf(acc, W2[u * 5 + 3], p3);
        p4 = fmaf(acc, W2[u * 5 + 4], p4);
    }
    // butterfly all-reduce across the 16-lane group
    p0 += SWZ(p0, 1); p1 += SWZ(p1, 1); p2 += SWZ(p2, 1); p3 += SWZ(p3, 1); p4 += SWZ(p4, 1);
    p0 += SWZ(p0, 2); p1 += SWZ(p1, 2); p2 += SWZ(p2, 2); p3 += SWZ(p3, 2); p4 += SWZ(p4, 2);
    p0 += SWZ(p0, 4); p1 += SWZ(p1, 4); p2 += SWZ(p2, 4); p3 += SWZ(p3, 4); p4 += SWZ(p4, 4);
    p0 += SWZ(p0, 8); p1 += SWZ(p1, 8); p2 += SWZ(p2, 8); p3 += SWZ(p3, 8); p4 += SWZ(p4, 8);

    p0 += b2[0]; p1 += b2[1]; p2 += b2[2]; p3 += b2[3]; p4 += b2[4];

    float mx = fmaxf(fmaxf(fmaxf(p0, p1), fmaxf(p2, p3)), p4);
    float e0 = EXP2F((p0 - mx) * LOG2E);
    float e1 = EXP2F((p1 - mx) * LOG2E);
    float e2 = EXP2F((p2 - mx) * LOG2E);
    float e3 = EXP2F((p3 - mx) * LOG2E);
    float e4 = EXP2F((p4 - mx) * LOG2E);
    float s = ((e0 + e1) + (e2 + e3)) + e4;
    float rs = RCPF(s);

    if (i16 == 0) {
        float* op = out + (size_t)seq * 5;
        op[0] = e0 * rs; op[1] = e1 * rs; op[2] = e2 * rs;
        op[3] = e3 * rs; op[4] = e4 * rs;
    }
}

extern "C" void kernel_launch(void* const* d_in, const int* in_sizes, int n_in,
                              void* d_out, int out_size, void* d_ws, size_t ws_size,
                              hipStream_t stream) {
    const float* x  = (const float*)d_in[0];
    const float* Wk = (const float*)d_in[1];
    const float* Wr = (const float*)d_in[2];
    const float* bg = (const float*)d_in[3];
    const float* W1 = (const float*)d_in[4];
    const float* b1 = (const float*)d_in[5];
    const float* W2 = (const float*)d_in[6];
    const float* b2 = (const float*)d_in[7];
    float* out = (float*)d_out;

    const int B = in_sizes[0] / (TLEN * 16);   // 4096
    dim3 block(256);
    dim3 grid(B / 16);                         // 16 seqs per block (4 per wave)
    lstm_mlp_kernel<<<grid, block, 0, stream>>>(x, Wk, Wr, bg, W1, b1, W2, b2, out, B);
}